// Round 1
// baseline (325.537 us; speedup 1.0000x reference)
//
#include <hip/hip_runtime.h>

#define N_NODES 50000
#define N_EDGES 800000
#define D 64

// ---- 1. xw = x @ W  (per-block: 4 rows, W staged in LDS) ----
__global__ __launch_bounds__(256) void k_matmul(const float* __restrict__ x,
                                                const float* __restrict__ W,
                                                float* __restrict__ xw) {
    __shared__ float Wl[D * D];
    __shared__ float xl[4 * D];
    int tid = threadIdx.x;
    for (int i = tid; i < D * D; i += 256) Wl[i] = W[i];
    int r = blockIdx.x * 4 + (tid >> 6);
    int c = tid & 63;
    if (r < N_NODES) xl[tid] = x[r * D + c];
    __syncthreads();
    if (r >= N_NODES) return;
    const float* xr = &xl[(tid >> 6) * D];
    float acc = 0.f;
#pragma unroll
    for (int k = 0; k < D; ++k) acc = fmaf(xr[k], Wl[k * D + c], acc);
    xw[r * D + c] = acc;
}

// ---- 2a. degree histogram over target nodes ----
__global__ __launch_bounds__(256) void k_deg(const int* __restrict__ col,
                                             int* __restrict__ deg) {
    int e = blockIdx.x * blockDim.x + threadIdx.x;
    if (e < N_EDGES) atomicAdd(&deg[col[e]], 1);
}

// ---- 2b. dis[i] = rsqrt(deg[i] + 1)   (+1 = self loop) ----
__global__ __launch_bounds__(256) void k_dis(const int* __restrict__ deg,
                                             float* __restrict__ dis) {
    int i = blockIdx.x * blockDim.x + threadIdx.x;
    if (i < N_NODES) dis[i] = rsqrtf((float)(deg[i] + 1));
}

// ---- 3. init out with self-loop contribution: out = dis^2 * xw ----
__global__ __launch_bounds__(256) void k_self(const float* __restrict__ xw,
                                              const float* __restrict__ dis,
                                              float* __restrict__ out) {
    int i = blockIdx.x * blockDim.x + threadIdx.x;
    if (i < N_NODES * D) {
        float s = dis[i >> 6];
        out[i] = s * s * xw[i];
    }
}

// ---- 4. edge scatter: one wave per edge, lane = channel ----
__global__ __launch_bounds__(256) void k_scatter(const int* __restrict__ ei,
                                                 const float* __restrict__ xw,
                                                 const float* __restrict__ dis,
                                                 float* __restrict__ out) {
    int e = (blockIdx.x * blockDim.x + threadIdx.x) >> 6;
    if (e >= N_EDGES) return;
    int lane = threadIdx.x & 63;
    int r = ei[e];             // source
    int c = ei[N_EDGES + e];   // target
    float w = dis[r] * dis[c];
    atomicAdd(&out[c * D + lane], w * xw[r * D + lane]);
}

// ---- 5. out = relu(out + b) ----
__global__ __launch_bounds__(256) void k_relu(float* __restrict__ out,
                                              const float* __restrict__ b) {
    int i = blockIdx.x * blockDim.x + threadIdx.x;
    if (i < N_NODES * D) {
        float v = out[i] + b[i & 63];
        out[i] = v > 0.f ? v : 0.f;
    }
}

extern "C" void kernel_launch(void* const* d_in, const int* in_sizes, int n_in,
                              void* d_out, int out_size, void* d_ws, size_t ws_size,
                              hipStream_t stream) {
    const float* x  = (const float*)d_in[0];
    const int*   ei = (const int*)d_in[1];   // [2, E] row-major, int32
    const float* W  = (const float*)d_in[2];
    const float* b  = (const float*)d_in[3];
    float* out = (float*)d_out;

    char* ws = (char*)d_ws;
    float* xw  = (float*)ws;                                       // N*D fp32 = 12.8 MB
    int*   deg = (int*)(ws + (size_t)N_NODES * D * sizeof(float)); // 200 KB
    float* dis = (float*)(ws + (size_t)N_NODES * D * sizeof(float)
                             + (size_t)N_NODES * sizeof(int));     // 200 KB

    hipMemsetAsync(deg, 0, N_NODES * sizeof(int), stream);

    k_matmul<<<(N_NODES + 3) / 4, 256, 0, stream>>>(x, W, xw);
    k_deg<<<(N_EDGES + 255) / 256, 256, 0, stream>>>(ei + N_EDGES, deg);
    k_dis<<<(N_NODES + 255) / 256, 256, 0, stream>>>(deg, dis);
    k_self<<<(N_NODES * D + 255) / 256, 256, 0, stream>>>(xw, dis, out);
    k_scatter<<<N_EDGES / 4, 256, 0, stream>>>(ei, xw, dis, out);
    k_relu<<<(N_NODES * D + 255) / 256, 256, 0, stream>>>(out, b);
}

// Round 2
// 264.416 us; speedup vs baseline: 1.2312x; 1.2312x over previous
//
#include <hip/hip_runtime.h>

#define N_NODES 50000
#define N_EDGES 800000
#define D 64
#define NB 196                 // ceil(50000/256)
#define NPAD (NB * 256)        // 50176, zero-padded degree region

// ---- 1. xw = x @ W  (per-block: 4 rows, W staged in LDS) ----
__global__ __launch_bounds__(256) void k_matmul(const float* __restrict__ x,
                                                const float* __restrict__ W,
                                                float* __restrict__ xw) {
    __shared__ float Wl[D * D];
    __shared__ float xl[4 * D];
    int tid = threadIdx.x;
    for (int i = tid; i < D * D; i += 256) Wl[i] = W[i];
    int r = blockIdx.x * 4 + (tid >> 6);
    int c = tid & 63;
    if (r < N_NODES) xl[tid] = x[r * D + c];
    __syncthreads();
    if (r >= N_NODES) return;
    const float* xr = &xl[(tid >> 6) * D];
    float acc = 0.f;
#pragma unroll
    for (int k = 0; k < D; ++k) acc = fmaf(xr[k], Wl[k * D + c], acc);
    xw[r * D + c] = acc;
}

// ---- 2. degree histogram over target nodes ----
__global__ __launch_bounds__(256) void k_deg(const int* __restrict__ col,
                                             int* __restrict__ deg) {
    int e = blockIdx.x * blockDim.x + threadIdx.x;
    if (e < N_EDGES) atomicAdd(&deg[col[e]], 1);
}

// ---- 3a. per-block sums of deg; also dis = rsqrt(deg+1) ----
__global__ __launch_bounds__(256) void k_scan1(const int* __restrict__ deg,
                                               float* __restrict__ dis,
                                               int* __restrict__ bsum) {
    __shared__ int s[256];
    int i = blockIdx.x * 256 + threadIdx.x;
    int d = deg[i];
    if (i < N_NODES) dis[i] = rsqrtf((float)(d + 1));
    s[threadIdx.x] = d;
    __syncthreads();
    for (int off = 128; off > 0; off >>= 1) {
        if (threadIdx.x < off) s[threadIdx.x] += s[threadIdx.x + off];
        __syncthreads();
    }
    if (threadIdx.x == 0) bsum[blockIdx.x] = s[0];
}

// ---- 3b. exclusive scan of the 196 block sums ----
__global__ void k_scan2(const int* __restrict__ bsum, int* __restrict__ boff) {
    if (threadIdx.x == 0) {
        int acc = 0;
        for (int b = 0; b < NB; ++b) { boff[b] = acc; acc += bsum[b]; }
    }
}

// ---- 3c. rowptr[i] = boff[block] + intra-block exclusive scan ----
__global__ __launch_bounds__(256) void k_scan3(const int* __restrict__ deg,
                                               const int* __restrict__ boff,
                                               int* __restrict__ rowptr) {
    __shared__ int s[256];
    int i = blockIdx.x * 256 + threadIdx.x;
    int d = deg[i];
    s[threadIdx.x] = d;
    __syncthreads();
    for (int off = 1; off < 256; off <<= 1) {
        int t = (threadIdx.x >= off) ? s[threadIdx.x - off] : 0;
        __syncthreads();
        s[threadIdx.x] += t;
        __syncthreads();
    }
    // s now holds the inclusive scan; exclusive = inclusive - d
    rowptr[i] = boff[blockIdx.x] + s[threadIdx.x] - d;
}

// ---- 4. bucket edges by target: esrc[rowptr[c] + cnt[c]++] = r ----
__global__ __launch_bounds__(256) void k_bucket(const int* __restrict__ ei,
                                                const int* __restrict__ rowptr,
                                                int* __restrict__ cnt,
                                                int* __restrict__ esrc) {
    int e = blockIdx.x * blockDim.x + threadIdx.x;
    if (e < N_EDGES) {
        int r = ei[e];
        int c = ei[N_EDGES + e];
        int pos = rowptr[c] + atomicAdd(&cnt[c], 1);
        esrc[pos] = r;
    }
}

// ---- 5. gather + self-loop + bias + relu (one wave per node, lane=channel) ----
__global__ __launch_bounds__(256) void k_gather(const int* __restrict__ rowptr,
                                                const int* __restrict__ esrc,
                                                const float* __restrict__ xw,
                                                const float* __restrict__ dis,
                                                const float* __restrict__ b,
                                                float* __restrict__ out) {
    int node = blockIdx.x * 4 + (threadIdx.x >> 6);
    if (node >= N_NODES) return;
    int lane = threadIdx.x & 63;
    int beg = rowptr[node], end = rowptr[node + 1];
    float acc = 0.f;
    for (int j = beg; j < end; ++j) {
        int r = esrc[j];
        acc = fmaf(dis[r], xw[r * D + lane], acc);
    }
    float dc = dis[node];
    float v = dc * fmaf(dc, xw[node * D + lane], acc) + b[lane];
    out[node * D + lane] = v > 0.f ? v : 0.f;
}

extern "C" void kernel_launch(void* const* d_in, const int* in_sizes, int n_in,
                              void* d_out, int out_size, void* d_ws, size_t ws_size,
                              hipStream_t stream) {
    const float* x  = (const float*)d_in[0];
    const int*   ei = (const int*)d_in[1];   // [2, E] row-major, int32
    const float* W  = (const float*)d_in[2];
    const float* b  = (const float*)d_in[3];
    float* out = (float*)d_out;

    char* ws = (char*)d_ws;
    size_t off = 0;
    float* xw     = (float*)(ws + off); off += (size_t)N_NODES * D * sizeof(float); // 12.8 MB
    int*   deg    = (int*)  (ws + off); off += (size_t)NPAD * sizeof(int);
    int*   cnt    = (int*)  (ws + off); off += (size_t)NPAD * sizeof(int);
    float* dis    = (float*)(ws + off); off += (size_t)NPAD * sizeof(float);
    int*   rowptr = (int*)  (ws + off); off += (size_t)NPAD * sizeof(int);
    int*   bsum   = (int*)  (ws + off); off += (size_t)NB * sizeof(int);
    int*   boff   = (int*)  (ws + off); off += (size_t)NB * sizeof(int);
    int*   esrc   = (int*)  (ws + off); off += (size_t)N_EDGES * sizeof(int);

    // zero deg + cnt in one shot (adjacent)
    hipMemsetAsync(deg, 0, 2 * (size_t)NPAD * sizeof(int), stream);

    k_matmul<<<(N_NODES + 3) / 4, 256, 0, stream>>>(x, W, xw);
    k_deg<<<(N_EDGES + 255) / 256, 256, 0, stream>>>(ei + N_EDGES, deg);
    k_scan1<<<NB, 256, 0, stream>>>(deg, dis, bsum);
    k_scan2<<<1, 256, 0, stream>>>(bsum, boff);
    k_scan3<<<NB, 256, 0, stream>>>(deg, boff, rowptr);
    k_bucket<<<(N_EDGES + 255) / 256, 256, 0, stream>>>(ei, rowptr, cnt, esrc);
    k_gather<<<(N_NODES + 3) / 4, 256, 0, stream>>>(rowptr, esrc, xw, dis, b, out);
}

// Round 3
// 254.443 us; speedup vs baseline: 1.2794x; 1.0392x over previous
//
#include <hip/hip_runtime.h>

#define N_NODES 50000
#define N_EDGES 800000
#define D 64
#define NPAD 50176             // 1024 * 49, zero-padded degree region
#define CHUNK 49

// ---- 1. xw = x @ W  (16 rows/block, W staged in LDS once) ----
__global__ __launch_bounds__(256) void k_matmul(const float* __restrict__ x,
                                                const float* __restrict__ W,
                                                float* __restrict__ xw) {
    __shared__ float Wl[D * D];
    __shared__ float xl[16 * D];
    int tid = threadIdx.x;
#pragma unroll
    for (int i = tid; i < D * D / 4; i += 256)
        ((float4*)Wl)[i] = ((const float4*)W)[i];
    int r0 = blockIdx.x * 16;
    ((float4*)xl)[tid] = ((const float4*)(x + (size_t)r0 * D))[tid];
    __syncthreads();
    int c  = tid & 63;
    int rg = tid >> 6;                 // 0..3; this thread does rows rg, rg+4, rg+8, rg+12
    float acc[4] = {0.f, 0.f, 0.f, 0.f};
    for (int k = 0; k < D; ++k) {
        float w = Wl[k * D + c];
#pragma unroll
        for (int q = 0; q < 4; ++q)
            acc[q] = fmaf(xl[(rg + 4 * q) * D + k], w, acc[q]);
    }
#pragma unroll
    for (int q = 0; q < 4; ++q)
        xw[(size_t)(r0 + rg + 4 * q) * D + c] = acc[q];
}

// ---- 2. degree histogram over target nodes (4 edges/thread) ----
__global__ __launch_bounds__(256) void k_deg(const int* __restrict__ col,
                                             int* __restrict__ deg) {
    int e4 = blockIdx.x * blockDim.x + threadIdx.x;
    if (e4 < N_EDGES / 4) {
        int4 c = ((const int4*)col)[e4];
        atomicAdd(&deg[c.x], 1);
        atomicAdd(&deg[c.y], 1);
        atomicAdd(&deg[c.z], 1);
        atomicAdd(&deg[c.w], 1);
    }
}

// ---- 3. fused scan: rowptr = exclusive_scan(deg), dis = rsqrt(deg+1) ----
__global__ __launch_bounds__(1024) void k_scan(const int* __restrict__ deg,
                                               float* __restrict__ dis,
                                               int* __restrict__ rowptr) {
    __shared__ int s[1024];
    int t = threadIdx.x;
    int base = t * CHUNK;
    int local[CHUNK];
    int sum = 0;
#pragma unroll
    for (int i = 0; i < CHUNK; ++i) { local[i] = deg[base + i]; sum += local[i]; }
    s[t] = sum;
    __syncthreads();
    for (int off = 1; off < 1024; off <<= 1) {
        int v = (t >= off) ? s[t - off] : 0;
        __syncthreads();
        s[t] += v;
        __syncthreads();
    }
    int run = s[t] - sum;              // exclusive prefix of this chunk
#pragma unroll
    for (int i = 0; i < CHUNK; ++i) {
        rowptr[base + i] = run;
        run += local[i];
        if (base + i < N_NODES) dis[base + i] = rsqrtf((float)(local[i] + 1));
    }
}

// ---- 4. bucket edges by target (4 edges/thread) ----
__global__ __launch_bounds__(256) void k_bucket(const int* __restrict__ ei,
                                                const int* __restrict__ rowptr,
                                                int* __restrict__ cnt,
                                                int* __restrict__ esrc) {
    int e4 = blockIdx.x * blockDim.x + threadIdx.x;
    if (e4 < N_EDGES / 4) {
        int4 r = ((const int4*)ei)[e4];
        int4 c = ((const int4*)(ei + N_EDGES))[e4];
        esrc[rowptr[c.x] + atomicAdd(&cnt[c.x], 1)] = r.x;
        esrc[rowptr[c.y] + atomicAdd(&cnt[c.y], 1)] = r.y;
        esrc[rowptr[c.z] + atomicAdd(&cnt[c.z], 1)] = r.z;
        esrc[rowptr[c.w] + atomicAdd(&cnt[c.w], 1)] = r.w;
    }
}

// ---- 5. gather + self-loop + bias + relu ----
// One wave per node. lane = (g:2)(c4:4): g = edge subgroup, c4 = channel quad.
// Each loop iteration: 4 edges in flight, float4 row loads.
__global__ __launch_bounds__(256) void k_gather(const int* __restrict__ rowptr,
                                                const int* __restrict__ esrc,
                                                const float* __restrict__ xw,
                                                const float* __restrict__ dis,
                                                const float* __restrict__ b,
                                                float* __restrict__ out) {
    int node = blockIdx.x * 4 + (threadIdx.x >> 6);
    int lane = threadIdx.x & 63;
    int g  = lane >> 4;                // 0..3
    int c4 = lane & 15;                // channel quad index
    int beg = rowptr[node], end = rowptr[node + 1];
    float4 acc = {0.f, 0.f, 0.f, 0.f};
    for (int j = beg + g; j < end; j += 4) {
        int r = esrc[j];
        float s = dis[r];
        float4 v = *(const float4*)(xw + (size_t)r * D + c4 * 4);
        acc.x = fmaf(s, v.x, acc.x);
        acc.y = fmaf(s, v.y, acc.y);
        acc.z = fmaf(s, v.z, acc.z);
        acc.w = fmaf(s, v.w, acc.w);
    }
#pragma unroll
    for (int m = 16; m <= 32; m <<= 1) {
        acc.x += __shfl_xor(acc.x, m, 64);
        acc.y += __shfl_xor(acc.y, m, 64);
        acc.z += __shfl_xor(acc.z, m, 64);
        acc.w += __shfl_xor(acc.w, m, 64);
    }
    if (g == 0) {
        float dc = dis[node];
        float4 xv = *(const float4*)(xw + (size_t)node * D + c4 * 4);
        float4 bv = *(const float4*)(b + c4 * 4);
        float4 o;
        o.x = dc * fmaf(dc, xv.x, acc.x) + bv.x;
        o.y = dc * fmaf(dc, xv.y, acc.y) + bv.y;
        o.z = dc * fmaf(dc, xv.z, acc.z) + bv.z;
        o.w = dc * fmaf(dc, xv.w, acc.w) + bv.w;
        o.x = o.x > 0.f ? o.x : 0.f;
        o.y = o.y > 0.f ? o.y : 0.f;
        o.z = o.z > 0.f ? o.z : 0.f;
        o.w = o.w > 0.f ? o.w : 0.f;
        *(float4*)(out + (size_t)node * D + c4 * 4) = o;
    }
}

extern "C" void kernel_launch(void* const* d_in, const int* in_sizes, int n_in,
                              void* d_out, int out_size, void* d_ws, size_t ws_size,
                              hipStream_t stream) {
    const float* x  = (const float*)d_in[0];
    const int*   ei = (const int*)d_in[1];   // [2, E] row-major, int32
    const float* W  = (const float*)d_in[2];
    const float* b  = (const float*)d_in[3];
    float* out = (float*)d_out;

    char* ws = (char*)d_ws;
    size_t off = 0;
    float* xw     = (float*)(ws + off); off += (size_t)N_NODES * D * sizeof(float);
    int*   deg    = (int*)  (ws + off); off += (size_t)NPAD * sizeof(int);
    int*   cnt    = (int*)  (ws + off); off += (size_t)NPAD * sizeof(int);
    float* dis    = (float*)(ws + off); off += (size_t)NPAD * sizeof(float);
    int*   rowptr = (int*)  (ws + off); off += (size_t)(NPAD + 16) * sizeof(int);
    int*   esrc   = (int*)  (ws + off); off += (size_t)N_EDGES * sizeof(int);

    hipMemsetAsync(deg, 0, 2 * (size_t)NPAD * sizeof(int), stream);

    k_matmul<<<N_NODES / 16, 256, 0, stream>>>(x, W, xw);
    k_deg<<<(N_EDGES / 4 + 255) / 256, 256, 0, stream>>>(ei + N_EDGES, deg);
    k_scan<<<1, 1024, 0, stream>>>(deg, dis, rowptr);
    k_bucket<<<(N_EDGES / 4 + 255) / 256, 256, 0, stream>>>(ei, rowptr, cnt, esrc);
    k_gather<<<N_NODES / 4, 256, 0, stream>>>(rowptr, esrc, xw, dis, b, out);
}

// Round 4
// 204.415 us; speedup vs baseline: 1.5925x; 1.2447x over previous
//
#include <hip/hip_runtime.h>

#define N_NODES 50000
#define N_EDGES 800000
#define D 64
#define NB 196                 // ceil(50000/256)
#define NPAD (NB * 256)        // 50176, zero-padded degree region

// ---- 1. xw = x @ W  (16 rows/block, W staged in LDS once) ----
__global__ __launch_bounds__(256) void k_matmul(const float* __restrict__ x,
                                                const float* __restrict__ W,
                                                float* __restrict__ xw) {
    __shared__ float Wl[D * D];
    __shared__ float xl[16 * D];
    int tid = threadIdx.x;
#pragma unroll
    for (int i = tid; i < D * D / 4; i += 256)
        ((float4*)Wl)[i] = ((const float4*)W)[i];
    int r0 = blockIdx.x * 16;
    ((float4*)xl)[tid] = ((const float4*)(x + (size_t)r0 * D))[tid];
    __syncthreads();
    int c  = tid & 63;
    int rg = tid >> 6;                 // 0..3; this thread does rows rg, rg+4, rg+8, rg+12
    float acc[4] = {0.f, 0.f, 0.f, 0.f};
    for (int k = 0; k < D; ++k) {
        float w = Wl[k * D + c];
#pragma unroll
        for (int q = 0; q < 4; ++q)
            acc[q] = fmaf(xl[(rg + 4 * q) * D + k], w, acc[q]);
    }
#pragma unroll
    for (int q = 0; q < 4; ++q)
        xw[(size_t)(r0 + rg + 4 * q) * D + c] = acc[q];
}

// ---- 2. degree histogram over target nodes (4 edges/thread) ----
__global__ __launch_bounds__(256) void k_deg(const int* __restrict__ col,
                                             int* __restrict__ deg) {
    int e4 = blockIdx.x * blockDim.x + threadIdx.x;
    if (e4 < N_EDGES / 4) {
        int4 c = ((const int4*)col)[e4];
        atomicAdd(&deg[c.x], 1);
        atomicAdd(&deg[c.y], 1);
        atomicAdd(&deg[c.z], 1);
        atomicAdd(&deg[c.w], 1);
    }
}

// ---- 3a. per-block sums of deg; also dis = rsqrt(deg+1) ----
__global__ __launch_bounds__(256) void k_scan1(const int* __restrict__ deg,
                                               float* __restrict__ dis,
                                               int* __restrict__ bsum) {
    __shared__ int s[256];
    int i = blockIdx.x * 256 + threadIdx.x;
    int d = deg[i];
    dis[i] = rsqrtf((float)(d + 1));   // NPAD region: harmless garbage
    s[threadIdx.x] = d;
    __syncthreads();
    for (int off = 128; off > 0; off >>= 1) {
        if (threadIdx.x < off) s[threadIdx.x] += s[threadIdx.x + off];
        __syncthreads();
    }
    if (threadIdx.x == 0) bsum[blockIdx.x] = s[0];
}

// ---- 3b. parallel exclusive scan of the 196 block sums (1 block, LDS) ----
__global__ __launch_bounds__(256) void k_scan2(const int* __restrict__ bsum,
                                               int* __restrict__ boff) {
    __shared__ int s[256];
    int t = threadIdx.x;
    int v = (t < NB) ? bsum[t] : 0;
    s[t] = v;
    __syncthreads();
    for (int off = 1; off < 256; off <<= 1) {
        int u = (t >= off) ? s[t - off] : 0;
        __syncthreads();
        s[t] += u;
        __syncthreads();
    }
    if (t < NB) boff[t] = s[t] - v;    // exclusive
}

// ---- 3c. rowptr[i] = boff[block] + intra-block exclusive scan ----
__global__ __launch_bounds__(256) void k_scan3(const int* __restrict__ deg,
                                               const int* __restrict__ boff,
                                               int* __restrict__ rowptr) {
    __shared__ int s[256];
    int i = blockIdx.x * 256 + threadIdx.x;
    int d = deg[i];
    s[threadIdx.x] = d;
    __syncthreads();
    for (int off = 1; off < 256; off <<= 1) {
        int t = (threadIdx.x >= off) ? s[threadIdx.x - off] : 0;
        __syncthreads();
        s[threadIdx.x] += t;
        __syncthreads();
    }
    rowptr[i] = boff[blockIdx.x] + s[threadIdx.x] - d;   // exclusive
}

// ---- 4. bucket edges by target (4 edges/thread) ----
__global__ __launch_bounds__(256) void k_bucket(const int* __restrict__ ei,
                                                const int* __restrict__ rowptr,
                                                int* __restrict__ cnt,
                                                int* __restrict__ esrc) {
    int e4 = blockIdx.x * blockDim.x + threadIdx.x;
    if (e4 < N_EDGES / 4) {
        int4 r = ((const int4*)ei)[e4];
        int4 c = ((const int4*)(ei + N_EDGES))[e4];
        esrc[rowptr[c.x] + atomicAdd(&cnt[c.x], 1)] = r.x;
        esrc[rowptr[c.y] + atomicAdd(&cnt[c.y], 1)] = r.y;
        esrc[rowptr[c.z] + atomicAdd(&cnt[c.z], 1)] = r.z;
        esrc[rowptr[c.w] + atomicAdd(&cnt[c.w], 1)] = r.w;
    }
}

// ---- 5. gather + self-loop + bias + relu ----
// One wave per node. lane = (g:2)(c4:4): g = edge subgroup, c4 = channel quad.
__global__ __launch_bounds__(256) void k_gather(const int* __restrict__ rowptr,
                                                const int* __restrict__ esrc,
                                                const float* __restrict__ xw,
                                                const float* __restrict__ dis,
                                                const float* __restrict__ b,
                                                float* __restrict__ out) {
    int node = blockIdx.x * 4 + (threadIdx.x >> 6);
    int lane = threadIdx.x & 63;
    int g  = lane >> 4;                // 0..3
    int c4 = lane & 15;                // channel quad index
    int beg = rowptr[node], end = rowptr[node + 1];
    float4 acc = {0.f, 0.f, 0.f, 0.f};
    for (int j = beg + g; j < end; j += 4) {
        int r = esrc[j];
        float s = dis[r];
        float4 v = *(const float4*)(xw + (size_t)r * D + c4 * 4);
        acc.x = fmaf(s, v.x, acc.x);
        acc.y = fmaf(s, v.y, acc.y);
        acc.z = fmaf(s, v.z, acc.z);
        acc.w = fmaf(s, v.w, acc.w);
    }
#pragma unroll
    for (int m = 16; m <= 32; m <<= 1) {
        acc.x += __shfl_xor(acc.x, m, 64);
        acc.y += __shfl_xor(acc.y, m, 64);
        acc.z += __shfl_xor(acc.z, m, 64);
        acc.w += __shfl_xor(acc.w, m, 64);
    }
    if (g == 0) {
        float dc = dis[node];
        float4 xv = *(const float4*)(xw + (size_t)node * D + c4 * 4);
        float4 bv = *(const float4*)(b + c4 * 4);
        float4 o;
        o.x = dc * fmaf(dc, xv.x, acc.x) + bv.x;
        o.y = dc * fmaf(dc, xv.y, acc.y) + bv.y;
        o.z = dc * fmaf(dc, xv.z, acc.z) + bv.z;
        o.w = dc * fmaf(dc, xv.w, acc.w) + bv.w;
        o.x = o.x > 0.f ? o.x : 0.f;
        o.y = o.y > 0.f ? o.y : 0.f;
        o.z = o.z > 0.f ? o.z : 0.f;
        o.w = o.w > 0.f ? o.w : 0.f;
        *(float4*)(out + (size_t)node * D + c4 * 4) = o;
    }
}

extern "C" void kernel_launch(void* const* d_in, const int* in_sizes, int n_in,
                              void* d_out, int out_size, void* d_ws, size_t ws_size,
                              hipStream_t stream) {
    const float* x  = (const float*)d_in[0];
    const int*   ei = (const int*)d_in[1];   // [2, E] row-major, int32
    const float* W  = (const float*)d_in[2];
    const float* b  = (const float*)d_in[3];
    float* out = (float*)d_out;

    char* ws = (char*)d_ws;
    size_t off = 0;
    float* xw     = (float*)(ws + off); off += (size_t)N_NODES * D * sizeof(float);
    int*   deg    = (int*)  (ws + off); off += (size_t)NPAD * sizeof(int);
    int*   cnt    = (int*)  (ws + off); off += (size_t)NPAD * sizeof(int);
    float* dis    = (float*)(ws + off); off += (size_t)NPAD * sizeof(float);
    int*   rowptr = (int*)  (ws + off); off += (size_t)(NPAD + 16) * sizeof(int);
    int*   bsum   = (int*)  (ws + off); off += (size_t)256 * sizeof(int);
    int*   boff   = (int*)  (ws + off); off += (size_t)256 * sizeof(int);
    int*   esrc   = (int*)  (ws + off); off += (size_t)N_EDGES * sizeof(int);

    hipMemsetAsync(deg, 0, 2 * (size_t)NPAD * sizeof(int), stream);

    k_matmul<<<N_NODES / 16, 256, 0, stream>>>(x, W, xw);
    k_deg<<<(N_EDGES / 4 + 255) / 256, 256, 0, stream>>>(ei + N_EDGES, deg);
    k_scan1<<<NB, 256, 0, stream>>>(deg, dis, bsum);
    k_scan2<<<1, 256, 0, stream>>>(bsum, boff);
    k_scan3<<<NB, 256, 0, stream>>>(deg, boff, rowptr);
    k_bucket<<<(N_EDGES / 4 + 255) / 256, 256, 0, stream>>>(ei, rowptr, cnt, esrc);
    k_gather<<<N_NODES / 4, 256, 0, stream>>>(rowptr, esrc, xw, dis, b, out);
}

// Round 5
// 172.336 us; speedup vs baseline: 1.8890x; 1.1861x over previous
//
#include <hip/hip_runtime.h>

#define N_NODES 50000
#define N_EDGES 800000
#define D 64
#define NB 196                 // ceil(50000/256)
#define NPAD (NB * 256)        // 50176, zero-padded degree region

// ---- 1. xw = x @ W  (16 rows/block, W staged in LDS once) ----
__global__ __launch_bounds__(256) void k_matmul(const float* __restrict__ x,
                                                const float* __restrict__ W,
                                                float* __restrict__ xw) {
    __shared__ float Wl[D * D];
    __shared__ float xl[16 * D];
    int tid = threadIdx.x;
#pragma unroll
    for (int i = tid; i < D * D / 4; i += 256)
        ((float4*)Wl)[i] = ((const float4*)W)[i];
    int r0 = blockIdx.x * 16;
    ((float4*)xl)[tid] = ((const float4*)(x + (size_t)r0 * D))[tid];
    __syncthreads();
    int c  = tid & 63;
    int rg = tid >> 6;                 // 0..3; rows rg, rg+4, rg+8, rg+12
    float acc[4] = {0.f, 0.f, 0.f, 0.f};
    for (int k = 0; k < D; ++k) {
        float w = Wl[k * D + c];
#pragma unroll
        for (int q = 0; q < 4; ++q)
            acc[q] = fmaf(xl[(rg + 4 * q) * D + k], w, acc[q]);
    }
#pragma unroll
    for (int q = 0; q < 4; ++q)
        xw[(size_t)(r0 + rg + 4 * q) * D + c] = acc[q];
}

// ---- 2. degree histogram + per-edge rank (old count) ----
__global__ __launch_bounds__(256) void k_degrank(const int* __restrict__ col,
                                                 int* __restrict__ deg,
                                                 int* __restrict__ rank) {
    int e4 = blockIdx.x * blockDim.x + threadIdx.x;
    if (e4 < N_EDGES / 4) {
        int4 c = ((const int4*)col)[e4];
        int4 k;
        k.x = atomicAdd(&deg[c.x], 1);
        k.y = atomicAdd(&deg[c.y], 1);
        k.z = atomicAdd(&deg[c.z], 1);
        k.w = atomicAdd(&deg[c.w], 1);
        ((int4*)rank)[e4] = k;
    }
}

// ---- 3a. per-block sums of deg; also dis = rsqrt(deg+1) ----
__global__ __launch_bounds__(256) void k_scan1(const int* __restrict__ deg,
                                               float* __restrict__ dis,
                                               int* __restrict__ bsum) {
    __shared__ int s[256];
    int i = blockIdx.x * 256 + threadIdx.x;
    int d = deg[i];
    dis[i] = rsqrtf((float)(d + 1));
    s[threadIdx.x] = d;
    __syncthreads();
    for (int off = 128; off > 0; off >>= 1) {
        if (threadIdx.x < off) s[threadIdx.x] += s[threadIdx.x + off];
        __syncthreads();
    }
    if (threadIdx.x == 0) bsum[blockIdx.x] = s[0];
}

// ---- 3b. parallel exclusive scan of the 196 block sums ----
__global__ __launch_bounds__(256) void k_scan2(const int* __restrict__ bsum,
                                               int* __restrict__ boff) {
    __shared__ int s[256];
    int t = threadIdx.x;
    int v = (t < NB) ? bsum[t] : 0;
    s[t] = v;
    __syncthreads();
    for (int off = 1; off < 256; off <<= 1) {
        int u = (t >= off) ? s[t - off] : 0;
        __syncthreads();
        s[t] += u;
        __syncthreads();
    }
    if (t < NB) boff[t] = s[t] - v;
}

// ---- 3c. rowptr[i] = boff[block] + intra-block exclusive scan ----
__global__ __launch_bounds__(256) void k_scan3(const int* __restrict__ deg,
                                               const int* __restrict__ boff,
                                               int* __restrict__ rowptr) {
    __shared__ int s[256];
    int i = blockIdx.x * 256 + threadIdx.x;
    int d = deg[i];
    s[threadIdx.x] = d;
    __syncthreads();
    for (int off = 1; off < 256; off <<= 1) {
        int t = (threadIdx.x >= off) ? s[threadIdx.x - off] : 0;
        __syncthreads();
        s[threadIdx.x] += t;
        __syncthreads();
    }
    rowptr[i] = boff[blockIdx.x] + s[threadIdx.x] - d;
}

// ---- 4. bucket edges by target — NO atomics (rank precomputed) ----
__global__ __launch_bounds__(256) void k_bucket(const int* __restrict__ ei,
                                                const int* __restrict__ rowptr,
                                                const int* __restrict__ rank,
                                                int* __restrict__ esrc) {
    int e4 = blockIdx.x * blockDim.x + threadIdx.x;
    if (e4 < N_EDGES / 4) {
        int4 r = ((const int4*)ei)[e4];
        int4 c = ((const int4*)(ei + N_EDGES))[e4];
        int4 k = ((const int4*)rank)[e4];
        esrc[rowptr[c.x] + k.x] = r.x;
        esrc[rowptr[c.y] + k.y] = r.y;
        esrc[rowptr[c.z] + k.z] = r.z;
        esrc[rowptr[c.w] + k.w] = r.w;
    }
}

// ---- 5. gather + self-loop + bias + relu ----
// One wave per node. lane = (g:2)(c4:4). 2x unrolled: 8 edges in flight/wave.
__global__ __launch_bounds__(256) void k_gather(const int* __restrict__ rowptr,
                                                const int* __restrict__ esrc,
                                                const float* __restrict__ xw,
                                                const float* __restrict__ dis,
                                                const float* __restrict__ b,
                                                float* __restrict__ out) {
    int node = blockIdx.x * 4 + (threadIdx.x >> 6);
    int lane = threadIdx.x & 63;
    int g  = lane >> 4;                // 0..3
    int c4 = lane & 15;                // channel quad index
    int beg = rowptr[node], end = rowptr[node + 1];
    float4 acc0 = {0.f, 0.f, 0.f, 0.f};
    float4 acc1 = {0.f, 0.f, 0.f, 0.f};
    int j = beg + g;
    for (; j + 4 < end; j += 8) {
        int r0 = esrc[j];
        int r1 = esrc[j + 4];
        float s0 = dis[r0];
        float s1 = dis[r1];
        float4 v0 = *(const float4*)(xw + (size_t)r0 * D + c4 * 4);
        float4 v1 = *(const float4*)(xw + (size_t)r1 * D + c4 * 4);
        acc0.x = fmaf(s0, v0.x, acc0.x);
        acc0.y = fmaf(s0, v0.y, acc0.y);
        acc0.z = fmaf(s0, v0.z, acc0.z);
        acc0.w = fmaf(s0, v0.w, acc0.w);
        acc1.x = fmaf(s1, v1.x, acc1.x);
        acc1.y = fmaf(s1, v1.y, acc1.y);
        acc1.z = fmaf(s1, v1.z, acc1.z);
        acc1.w = fmaf(s1, v1.w, acc1.w);
    }
    if (j < end) {
        int r = esrc[j];
        float s = dis[r];
        float4 v = *(const float4*)(xw + (size_t)r * D + c4 * 4);
        acc0.x = fmaf(s, v.x, acc0.x);
        acc0.y = fmaf(s, v.y, acc0.y);
        acc0.z = fmaf(s, v.z, acc0.z);
        acc0.w = fmaf(s, v.w, acc0.w);
    }
    acc0.x += acc1.x; acc0.y += acc1.y; acc0.z += acc1.z; acc0.w += acc1.w;
#pragma unroll
    for (int m = 16; m <= 32; m <<= 1) {
        acc0.x += __shfl_xor(acc0.x, m, 64);
        acc0.y += __shfl_xor(acc0.y, m, 64);
        acc0.z += __shfl_xor(acc0.z, m, 64);
        acc0.w += __shfl_xor(acc0.w, m, 64);
    }
    if (g == 0) {
        float dc = dis[node];
        float4 xv = *(const float4*)(xw + (size_t)node * D + c4 * 4);
        float4 bv = *(const float4*)(b + c4 * 4);
        float4 o;
        o.x = dc * fmaf(dc, xv.x, acc0.x) + bv.x;
        o.y = dc * fmaf(dc, xv.y, acc0.y) + bv.y;
        o.z = dc * fmaf(dc, xv.z, acc0.z) + bv.z;
        o.w = dc * fmaf(dc, xv.w, acc0.w) + bv.w;
        o.x = o.x > 0.f ? o.x : 0.f;
        o.y = o.y > 0.f ? o.y : 0.f;
        o.z = o.z > 0.f ? o.z : 0.f;
        o.w = o.w > 0.f ? o.w : 0.f;
        *(float4*)(out + (size_t)node * D + c4 * 4) = o;
    }
}

extern "C" void kernel_launch(void* const* d_in, const int* in_sizes, int n_in,
                              void* d_out, int out_size, void* d_ws, size_t ws_size,
                              hipStream_t stream) {
    const float* x  = (const float*)d_in[0];
    const int*   ei = (const int*)d_in[1];   // [2, E] row-major, int32
    const float* W  = (const float*)d_in[2];
    const float* b  = (const float*)d_in[3];
    float* out = (float*)d_out;

    char* ws = (char*)d_ws;
    size_t off = 0;
    float* xw     = (float*)(ws + off); off += (size_t)N_NODES * D * sizeof(float);
    int*   deg    = (int*)  (ws + off); off += (size_t)NPAD * sizeof(int);
    float* dis    = (float*)(ws + off); off += (size_t)NPAD * sizeof(float);
    int*   rowptr = (int*)  (ws + off); off += (size_t)(NPAD + 16) * sizeof(int);
    int*   bsum   = (int*)  (ws + off); off += (size_t)256 * sizeof(int);
    int*   boff   = (int*)  (ws + off); off += (size_t)256 * sizeof(int);
    int*   rank   = (int*)  (ws + off); off += (size_t)N_EDGES * sizeof(int);
    int*   esrc   = (int*)  (ws + off); off += (size_t)N_EDGES * sizeof(int);

    hipMemsetAsync(deg, 0, (size_t)NPAD * sizeof(int), stream);

    k_matmul<<<N_NODES / 16, 256, 0, stream>>>(x, W, xw);
    k_degrank<<<(N_EDGES / 4 + 255) / 256, 256, 0, stream>>>(ei + N_EDGES, deg, rank);
    k_scan1<<<NB, 256, 0, stream>>>(deg, dis, bsum);
    k_scan2<<<1, 256, 0, stream>>>(bsum, boff);
    k_scan3<<<NB, 256, 0, stream>>>(deg, boff, rowptr);
    k_bucket<<<(N_EDGES / 4 + 255) / 256, 256, 0, stream>>>(ei, rowptr, rank, esrc);
    k_gather<<<N_NODES / 4, 256, 0, stream>>>(rowptr, esrc, xw, dis, b, out);
}

// Round 6
// 161.154 us; speedup vs baseline: 2.0200x; 1.0694x over previous
//
#include <hip/hip_runtime.h>

#define N_NODES 50000
#define N_EDGES 800000
#define D 64
#define NB 196                 // ceil(50000/256)
#define NPAD (NB * 256)        // 50176, zero-padded degree region
#define NBLK_DEG ((N_EDGES / 4 + 255) / 256)   // 782
#define NBLK_MM (N_NODES / 16)                 // 3125

typedef _Float16 half4 __attribute__((ext_vector_type(4)));

// ---- 1+2 fused: degrank (blocks [0,NBLK_DEG)) + matmul (rest) ----
// degrank: atomic-latency-bound, idle VALU; matmul: VALU-bound. Co-resident
// blocks overlap the two pipes (cost ~ max, not sum).
__global__ __launch_bounds__(256) void k_mm_degrank(const float* __restrict__ x,
                                                    const float* __restrict__ W,
                                                    _Float16* __restrict__ xwh,
                                                    const int* __restrict__ col,
                                                    int* __restrict__ deg,
                                                    int* __restrict__ rank) {
    __shared__ float Wl[D * D];
    __shared__ float xl[16 * D];
    if (blockIdx.x < NBLK_DEG) {
        int e4 = blockIdx.x * 256 + threadIdx.x;
        if (e4 < N_EDGES / 4) {
            int4 c = ((const int4*)col)[e4];
            int4 k;
            k.x = atomicAdd(&deg[c.x], 1);
            k.y = atomicAdd(&deg[c.y], 1);
            k.z = atomicAdd(&deg[c.z], 1);
            k.w = atomicAdd(&deg[c.w], 1);
            ((int4*)rank)[e4] = k;
        }
        return;
    }
    int bid = blockIdx.x - NBLK_DEG;
    int tid = threadIdx.x;
#pragma unroll
    for (int i = tid; i < D * D / 4; i += 256)
        ((float4*)Wl)[i] = ((const float4*)W)[i];
    int r0 = bid * 16;
    ((float4*)xl)[tid] = ((const float4*)(x + (size_t)r0 * D))[tid];
    __syncthreads();
    int c  = tid & 63;
    int rg = tid >> 6;                 // rows rg, rg+4, rg+8, rg+12
    float acc[4] = {0.f, 0.f, 0.f, 0.f};
    for (int k = 0; k < D; ++k) {
        float w = Wl[k * D + c];
#pragma unroll
        for (int q = 0; q < 4; ++q)
            acc[q] = fmaf(xl[(rg + 4 * q) * D + k], w, acc[q]);
    }
#pragma unroll
    for (int q = 0; q < 4; ++q)
        xwh[(size_t)(r0 + rg + 4 * q) * D + c] = (_Float16)acc[q];
}

// ---- 3a. per-block sums of deg; also dis = rsqrt(deg+1) ----
__global__ __launch_bounds__(256) void k_scan1(const int* __restrict__ deg,
                                               float* __restrict__ dis,
                                               int* __restrict__ bsum) {
    __shared__ int s[256];
    int i = blockIdx.x * 256 + threadIdx.x;
    int d = deg[i];
    dis[i] = rsqrtf((float)(d + 1));
    s[threadIdx.x] = d;
    __syncthreads();
    for (int off = 128; off > 0; off >>= 1) {
        if (threadIdx.x < off) s[threadIdx.x] += s[threadIdx.x + off];
        __syncthreads();
    }
    if (threadIdx.x == 0) bsum[blockIdx.x] = s[0];
}

// ---- 3b. rowptr: every block re-scans the 196 block sums in LDS (kills scan2) ----
__global__ __launch_bounds__(256) void k_scan3(const int* __restrict__ deg,
                                               const int* __restrict__ bsum,
                                               int* __restrict__ rowptr) {
    __shared__ int s[256];
    __shared__ int sb[256];
    int t = threadIdx.x;
    int i = blockIdx.x * 256 + t;
    int d = deg[i];
    s[t] = d;
    sb[t] = (t < NB) ? bsum[t] : 0;
    __syncthreads();
    for (int off = 1; off < 256; off <<= 1) {
        int u1 = (t >= off) ? s[t - off] : 0;
        int u2 = (t >= off) ? sb[t - off] : 0;
        __syncthreads();
        s[t] += u1;
        sb[t] += u2;
        __syncthreads();
    }
    int boff = (blockIdx.x == 0) ? 0 : sb[blockIdx.x - 1];  // exclusive block offset
    rowptr[i] = boff + s[t] - d;                            // exclusive intra-block
}

// ---- 4. bucket edges by target — NO atomics (rank precomputed) ----
__global__ __launch_bounds__(256) void k_bucket(const int* __restrict__ ei,
                                                const int* __restrict__ rowptr,
                                                const int* __restrict__ rank,
                                                int* __restrict__ esrc) {
    int e4 = blockIdx.x * blockDim.x + threadIdx.x;
    if (e4 < N_EDGES / 4) {
        int4 r = ((const int4*)ei)[e4];
        int4 c = ((const int4*)(ei + N_EDGES))[e4];
        int4 k = ((const int4*)rank)[e4];
        esrc[rowptr[c.x] + k.x] = r.x;
        esrc[rowptr[c.y] + k.y] = r.y;
        esrc[rowptr[c.z] + k.z] = r.z;
        esrc[rowptr[c.w] + k.w] = r.w;
    }
}

// ---- 5. gather + self-loop + bias + relu (fp16 xw rows, 8 edges in flight) ----
__global__ __launch_bounds__(256) void k_gather(const int* __restrict__ rowptr,
                                                const int* __restrict__ esrc,
                                                const _Float16* __restrict__ xwh,
                                                const float* __restrict__ dis,
                                                const float* __restrict__ b,
                                                float* __restrict__ out) {
    int node = blockIdx.x * 4 + (threadIdx.x >> 6);
    int lane = threadIdx.x & 63;
    int g  = lane >> 4;                // 0..3 edge subgroup
    int c4 = lane & 15;                // channel quad index
    int beg = rowptr[node], end = rowptr[node + 1];
    float4 acc0 = {0.f, 0.f, 0.f, 0.f};
    float4 acc1 = {0.f, 0.f, 0.f, 0.f};
    int j = beg + g;
    for (; j + 4 < end; j += 8) {
        int r0 = esrc[j];
        int r1 = esrc[j + 4];
        float s0 = dis[r0];
        float s1 = dis[r1];
        half4 v0 = *(const half4*)(xwh + (size_t)r0 * D + c4 * 4);
        half4 v1 = *(const half4*)(xwh + (size_t)r1 * D + c4 * 4);
        acc0.x = fmaf(s0, (float)v0.x, acc0.x);
        acc0.y = fmaf(s0, (float)v0.y, acc0.y);
        acc0.z = fmaf(s0, (float)v0.z, acc0.z);
        acc0.w = fmaf(s0, (float)v0.w, acc0.w);
        acc1.x = fmaf(s1, (float)v1.x, acc1.x);
        acc1.y = fmaf(s1, (float)v1.y, acc1.y);
        acc1.z = fmaf(s1, (float)v1.z, acc1.z);
        acc1.w = fmaf(s1, (float)v1.w, acc1.w);
    }
    if (j < end) {
        int r = esrc[j];
        float s = dis[r];
        half4 v = *(const half4*)(xwh + (size_t)r * D + c4 * 4);
        acc0.x = fmaf(s, (float)v.x, acc0.x);
        acc0.y = fmaf(s, (float)v.y, acc0.y);
        acc0.z = fmaf(s, (float)v.z, acc0.z);
        acc0.w = fmaf(s, (float)v.w, acc0.w);
    }
    acc0.x += acc1.x; acc0.y += acc1.y; acc0.z += acc1.z; acc0.w += acc1.w;
#pragma unroll
    for (int m = 16; m <= 32; m <<= 1) {
        acc0.x += __shfl_xor(acc0.x, m, 64);
        acc0.y += __shfl_xor(acc0.y, m, 64);
        acc0.z += __shfl_xor(acc0.z, m, 64);
        acc0.w += __shfl_xor(acc0.w, m, 64);
    }
    if (g == 0) {
        float dc = dis[node];
        half4 xv = *(const half4*)(xwh + (size_t)node * D + c4 * 4);
        float4 bv = *(const float4*)(b + c4 * 4);
        float4 o;
        o.x = dc * fmaf(dc, (float)xv.x, acc0.x) + bv.x;
        o.y = dc * fmaf(dc, (float)xv.y, acc0.y) + bv.y;
        o.z = dc * fmaf(dc, (float)xv.z, acc0.z) + bv.z;
        o.w = dc * fmaf(dc, (float)xv.w, acc0.w) + bv.w;
        o.x = o.x > 0.f ? o.x : 0.f;
        o.y = o.y > 0.f ? o.y : 0.f;
        o.z = o.z > 0.f ? o.z : 0.f;
        o.w = o.w > 0.f ? o.w : 0.f;
        *(float4*)(out + (size_t)node * D + c4 * 4) = o;
    }
}

extern "C" void kernel_launch(void* const* d_in, const int* in_sizes, int n_in,
                              void* d_out, int out_size, void* d_ws, size_t ws_size,
                              hipStream_t stream) {
    const float* x  = (const float*)d_in[0];
    const int*   ei = (const int*)d_in[1];   // [2, E] row-major, int32
    const float* W  = (const float*)d_in[2];
    const float* b  = (const float*)d_in[3];
    float* out = (float*)d_out;

    char* ws = (char*)d_ws;
    size_t off = 0;
    _Float16* xwh = (_Float16*)(ws + off); off += (size_t)N_NODES * D * sizeof(_Float16);
    int*   deg    = (int*)  (ws + off); off += (size_t)NPAD * sizeof(int);
    float* dis    = (float*)(ws + off); off += (size_t)NPAD * sizeof(float);
    int*   rowptr = (int*)  (ws + off); off += (size_t)(NPAD + 16) * sizeof(int);
    int*   bsum   = (int*)  (ws + off); off += (size_t)256 * sizeof(int);
    int*   rank   = (int*)  (ws + off); off += (size_t)N_EDGES * sizeof(int);
    int*   esrc   = (int*)  (ws + off); off += (size_t)N_EDGES * sizeof(int);

    hipMemsetAsync(deg, 0, (size_t)NPAD * sizeof(int), stream);

    k_mm_degrank<<<NBLK_DEG + NBLK_MM, 256, 0, stream>>>(x, W, xwh, ei + N_EDGES, deg, rank);
    k_scan1<<<NB, 256, 0, stream>>>(deg, dis, bsum);
    k_scan3<<<NB, 256, 0, stream>>>(deg, bsum, rowptr);
    k_bucket<<<(N_EDGES / 4 + 255) / 256, 256, 0, stream>>>(ei, rowptr, rank, esrc);
    k_gather<<<N_NODES / 4, 256, 0, stream>>>(rowptr, esrc, xwh, dis, b, out);
}

// Round 7
// 153.643 us; speedup vs baseline: 2.1188x; 1.0489x over previous
//
#include <hip/hip_runtime.h>

#define N_NODES 50000
#define N_EDGES 800000
#define D 64
#define NB 196                 // ceil(50000/256)
#define NPAD (NB * 256)        // 50176, zero-padded degree region
#define NBLK_MM (N_NODES / 16)                 // 3125 matmul tiles
#define NBLK_DEG (N_EDGES / 256)               // 3125 deg chunks (1 edge/thread)

typedef _Float16 half4 __attribute__((ext_vector_type(4)));

// ---- 1+2 fused & interleaved: even blocks = matmul tile, odd = degrank ----
// degrank: atomic-latency-bound, idle VALU; matmul: VALU-bound. Interleaving
// makes both streams co-resident from t=0 (cost ~ max, not sum).
__global__ __launch_bounds__(256) void k_mm_degrank(const float* __restrict__ x,
                                                    const float* __restrict__ W,
                                                    _Float16* __restrict__ xwh,
                                                    const int* __restrict__ col,
                                                    int* __restrict__ deg,
                                                    int* __restrict__ rank) {
    __shared__ float Wl[D * D];
    __shared__ float xl[16 * D];
    int bid = blockIdx.x >> 1;
    if (blockIdx.x & 1) {
        int e = bid * 256 + threadIdx.x;
        int c = col[e];
        rank[e] = atomicAdd(&deg[c], 1);
        return;
    }
    int tid = threadIdx.x;
#pragma unroll
    for (int i = tid; i < D * D / 4; i += 256)
        ((float4*)Wl)[i] = ((const float4*)W)[i];
    int r0 = bid * 16;
    ((float4*)xl)[tid] = ((const float4*)(x + (size_t)r0 * D))[tid];
    __syncthreads();
    int c  = tid & 63;
    int rg = tid >> 6;                 // rows rg, rg+4, rg+8, rg+12
    float acc[4] = {0.f, 0.f, 0.f, 0.f};
    for (int k = 0; k < D; ++k) {
        float w = Wl[k * D + c];
#pragma unroll
        for (int q = 0; q < 4; ++q)
            acc[q] = fmaf(xl[(rg + 4 * q) * D + k], w, acc[q]);
    }
#pragma unroll
    for (int q = 0; q < 4; ++q)
        xwh[(size_t)(r0 + rg + 4 * q) * D + c] = (_Float16)acc[q];
}

// ---- 3a. per-block sums of deg; also dis = rsqrt(deg+1) ----
__global__ __launch_bounds__(256) void k_scan1(const int* __restrict__ deg,
                                               float* __restrict__ dis,
                                               int* __restrict__ bsum) {
    __shared__ int s[256];
    int i = blockIdx.x * 256 + threadIdx.x;
    int d = deg[i];
    dis[i] = rsqrtf((float)(d + 1));
    s[threadIdx.x] = d;
    __syncthreads();
    for (int off = 128; off > 0; off >>= 1) {
        if (threadIdx.x < off) s[threadIdx.x] += s[threadIdx.x + off];
        __syncthreads();
    }
    if (threadIdx.x == 0) bsum[blockIdx.x] = s[0];
}

// ---- 3b. rowptr: every block re-scans the 196 block sums in LDS ----
__global__ __launch_bounds__(256) void k_scan3(const int* __restrict__ deg,
                                               const int* __restrict__ bsum,
                                               int* __restrict__ rowptr) {
    __shared__ int s[256];
    __shared__ int sb[256];
    int t = threadIdx.x;
    int i = blockIdx.x * 256 + t;
    int d = deg[i];
    s[t] = d;
    sb[t] = (t < NB) ? bsum[t] : 0;
    __syncthreads();
    for (int off = 1; off < 256; off <<= 1) {
        int u1 = (t >= off) ? s[t - off] : 0;
        int u2 = (t >= off) ? sb[t - off] : 0;
        __syncthreads();
        s[t] += u1;
        sb[t] += u2;
        __syncthreads();
    }
    int boff = (blockIdx.x == 0) ? 0 : sb[blockIdx.x - 1];
    rowptr[i] = boff + s[t] - d;
}

// ---- 4. bucket: edata[rowptr[c]+rank] = {src, dis[src]} — no atomics ----
// The dis[r] gather lives here (feeds a fire-and-forget store) instead of on
// k_gather's latency-critical chain.
__global__ __launch_bounds__(256) void k_bucket(const int* __restrict__ ei,
                                                const int* __restrict__ rowptr,
                                                const int* __restrict__ rank,
                                                const float* __restrict__ dis,
                                                int2* __restrict__ edata) {
    int e4 = blockIdx.x * blockDim.x + threadIdx.x;
    if (e4 < N_EDGES / 4) {
        int4 r = ((const int4*)ei)[e4];
        int4 c = ((const int4*)(ei + N_EDGES))[e4];
        int4 k = ((const int4*)rank)[e4];
        int2 d0 = {r.x, __float_as_int(dis[r.x])};
        int2 d1 = {r.y, __float_as_int(dis[r.y])};
        int2 d2 = {r.z, __float_as_int(dis[r.z])};
        int2 d3 = {r.w, __float_as_int(dis[r.w])};
        edata[rowptr[c.x] + k.x] = d0;
        edata[rowptr[c.y] + k.y] = d1;
        edata[rowptr[c.z] + k.z] = d2;
        edata[rowptr[c.w] + k.w] = d3;
    }
}

// ---- 5. gather + self-loop + bias + relu (fp16 rows, 8 edges in flight) ----
__global__ __launch_bounds__(256) void k_gather(const int* __restrict__ rowptr,
                                                const int2* __restrict__ edata,
                                                const _Float16* __restrict__ xwh,
                                                const float* __restrict__ dis,
                                                const float* __restrict__ b,
                                                float* __restrict__ out) {
    int node = blockIdx.x * 4 + (threadIdx.x >> 6);
    int lane = threadIdx.x & 63;
    int g  = lane >> 4;                // 0..3 edge subgroup
    int c4 = lane & 15;                // channel quad index
    int beg = rowptr[node], end = rowptr[node + 1];
    float4 acc0 = {0.f, 0.f, 0.f, 0.f};
    float4 acc1 = {0.f, 0.f, 0.f, 0.f};
    int j = beg + g;
    for (; j + 4 < end; j += 8) {
        int2 e0 = edata[j];
        int2 e1 = edata[j + 4];
        float s0 = __int_as_float(e0.y);
        float s1 = __int_as_float(e1.y);
        half4 v0 = *(const half4*)(xwh + (size_t)e0.x * D + c4 * 4);
        half4 v1 = *(const half4*)(xwh + (size_t)e1.x * D + c4 * 4);
        acc0.x = fmaf(s0, (float)v0.x, acc0.x);
        acc0.y = fmaf(s0, (float)v0.y, acc0.y);
        acc0.z = fmaf(s0, (float)v0.z, acc0.z);
        acc0.w = fmaf(s0, (float)v0.w, acc0.w);
        acc1.x = fmaf(s1, (float)v1.x, acc1.x);
        acc1.y = fmaf(s1, (float)v1.y, acc1.y);
        acc1.z = fmaf(s1, (float)v1.z, acc1.z);
        acc1.w = fmaf(s1, (float)v1.w, acc1.w);
    }
    if (j < end) {
        int2 e0 = edata[j];
        float s = __int_as_float(e0.y);
        half4 v = *(const half4*)(xwh + (size_t)e0.x * D + c4 * 4);
        acc0.x = fmaf(s, (float)v.x, acc0.x);
        acc0.y = fmaf(s, (float)v.y, acc0.y);
        acc0.z = fmaf(s, (float)v.z, acc0.z);
        acc0.w = fmaf(s, (float)v.w, acc0.w);
    }
    acc0.x += acc1.x; acc0.y += acc1.y; acc0.z += acc1.z; acc0.w += acc1.w;
#pragma unroll
    for (int m = 16; m <= 32; m <<= 1) {
        acc0.x += __shfl_xor(acc0.x, m, 64);
        acc0.y += __shfl_xor(acc0.y, m, 64);
        acc0.z += __shfl_xor(acc0.z, m, 64);
        acc0.w += __shfl_xor(acc0.w, m, 64);
    }
    if (g == 0) {
        float dc = dis[node];
        half4 xv = *(const half4*)(xwh + (size_t)node * D + c4 * 4);
        float4 bv = *(const float4*)(b + c4 * 4);
        float4 o;
        o.x = dc * fmaf(dc, (float)xv.x, acc0.x) + bv.x;
        o.y = dc * fmaf(dc, (float)xv.y, acc0.y) + bv.y;
        o.z = dc * fmaf(dc, (float)xv.z, acc0.z) + bv.z;
        o.w = dc * fmaf(dc, (float)xv.w, acc0.w) + bv.w;
        o.x = o.x > 0.f ? o.x : 0.f;
        o.y = o.y > 0.f ? o.y : 0.f;
        o.z = o.z > 0.f ? o.z : 0.f;
        o.w = o.w > 0.f ? o.w : 0.f;
        *(float4*)(out + (size_t)node * D + c4 * 4) = o;
    }
}

extern "C" void kernel_launch(void* const* d_in, const int* in_sizes, int n_in,
                              void* d_out, int out_size, void* d_ws, size_t ws_size,
                              hipStream_t stream) {
    const float* x  = (const float*)d_in[0];
    const int*   ei = (const int*)d_in[1];   // [2, E] row-major, int32
    const float* W  = (const float*)d_in[2];
    const float* b  = (const float*)d_in[3];
    float* out = (float*)d_out;

    char* ws = (char*)d_ws;
    size_t off = 0;
    _Float16* xwh = (_Float16*)(ws + off); off += (size_t)N_NODES * D * sizeof(_Float16);
    int*   deg    = (int*)  (ws + off); off += (size_t)NPAD * sizeof(int);
    float* dis    = (float*)(ws + off); off += (size_t)NPAD * sizeof(float);
    int*   rowptr = (int*)  (ws + off); off += (size_t)(NPAD + 16) * sizeof(int);
    int*   bsum   = (int*)  (ws + off); off += (size_t)256 * sizeof(int);
    int*   rank   = (int*)  (ws + off); off += (size_t)N_EDGES * sizeof(int);
    int2*  edata  = (int2*) (ws + off); off += (size_t)N_EDGES * sizeof(int2);

    hipMemsetAsync(deg, 0, (size_t)NPAD * sizeof(int), stream);

    k_mm_degrank<<<NBLK_MM + NBLK_DEG, 256, 0, stream>>>(x, W, xwh, ei + N_EDGES, deg, rank);
    k_scan1<<<NB, 256, 0, stream>>>(deg, dis, bsum);
    k_scan3<<<NB, 256, 0, stream>>>(deg, bsum, rowptr);
    k_bucket<<<(N_EDGES / 4 + 255) / 256, 256, 0, stream>>>(ei, rowptr, rank, dis, edata);
    k_gather<<<N_NODES / 4, 256, 0, stream>>>(rowptr, edata, xwh, dis, b, out);
}